// Round 1
// baseline (1946.138 us; speedup 1.0000x reference)
//
#include <hip/hip_runtime.h>
#include <hip/hip_bf16.h>

#define B_  2
#define S_  2048
#define D_  512
#define H_  8
#define HD_ 64

// ============================================================================
// Projection: OUT[b,h,s,hd] = sum_d IN[b*S+s][d] * W[h*HD+hd][d] + bias[h*HD+hd]
// A = IN [4096 x 512] row-major, W [512 x 512] row-major (dot of rows: X @ W^T)
// ============================================================================
#define PBM 128
#define PBN 64
#define PBK 16

__global__ __launch_bounds__(256)
void proj_kernel(const float* __restrict__ in0, const float* __restrict__ in1,
                 const float* __restrict__ in2,
                 const float* __restrict__ Wq, const float* __restrict__ bq,
                 const float* __restrict__ Wk, const float* __restrict__ bk,
                 const float* __restrict__ Wv, const float* __restrict__ bv,
                 float* __restrict__ ws)
{
    const int which = blockIdx.z;
    const float* X    = which == 0 ? in0 : (which == 1 ? in1 : in2);
    const float* W    = which == 0 ? Wq  : (which == 1 ? Wk  : Wv);
    const float* bias = which == 0 ? bq  : (which == 1 ? bk  : bv);
    float* out = ws + (size_t)which * (B_ * H_ * S_ * HD_);

    __shared__ float As[PBK][PBM + 4];   // pad 4 -> store bank = (4k + row) % 32, 2-way max
    __shared__ float Bs[PBK][PBN + 4];

    const int m0 = blockIdx.x * PBM;
    const int n0 = blockIdx.y * PBN;
    const int t  = threadIdx.x;
    const int tx = t & 15;    // micro col group (4 cols)
    const int ty = t >> 4;    // micro row group (8 rows)
    const int lk = t & 15;    // k for staging loads
    const int lr = t >> 4;    // row group for staging loads

    float4 acc[8];
    #pragma unroll
    for (int i = 0; i < 8; ++i) acc[i] = make_float4(0.f, 0.f, 0.f, 0.f);

    for (int k0 = 0; k0 < D_; k0 += PBK) {
        #pragma unroll
        for (int p = 0; p < 8; ++p) {
            int row = lr + p * 16;
            As[lk][row] = X[(size_t)(m0 + row) * D_ + k0 + lk];
        }
        #pragma unroll
        for (int p = 0; p < 4; ++p) {
            int row = lr + p * 16;
            Bs[lk][row] = W[(size_t)(n0 + row) * D_ + k0 + lk];
        }
        __syncthreads();
        #pragma unroll
        for (int kk = 0; kk < PBK; ++kk) {
            const float4* arow = reinterpret_cast<const float4*>(&As[kk][ty * 8]);
            const float4* brow = reinterpret_cast<const float4*>(&Bs[kk][tx * 4]);
            float4 a0 = arow[0], a1 = arow[1];
            float4 bb = brow[0];
            float av[8] = {a0.x, a0.y, a0.z, a0.w, a1.x, a1.y, a1.z, a1.w};
            #pragma unroll
            for (int i = 0; i < 8; ++i) {
                acc[i].x = fmaf(av[i], bb.x, acc[i].x);
                acc[i].y = fmaf(av[i], bb.y, acc[i].y);
                acc[i].z = fmaf(av[i], bb.z, acc[i].z);
                acc[i].w = fmaf(av[i], bb.w, acc[i].w);
            }
        }
        __syncthreads();
    }

    // epilogue: add bias, scatter to [B,H,S,HD]
    const int h  = n0 >> 6;           // PBN==HD_ -> one head per block column
    const int n_base = n0 + tx * 4;
    float4 bv4 = *reinterpret_cast<const float4*>(&bias[n_base]);
    #pragma unroll
    for (int i = 0; i < 8; ++i) {
        int m  = m0 + ty * 8 + i;
        int bb = m >> 11;             // /S_
        int s  = m & (S_ - 1);
        float* orow = out + (((size_t)bb * H_ + h) * S_ + s) * HD_ + (n_base - n0);
        orow[0] = acc[i].x + bv4.x;
        orow[1] = acc[i].y + bv4.y;
        orow[2] = acc[i].z + bv4.z;
        orow[3] = acc[i].w + bv4.w;
    }
}

// ============================================================================
// Attention: one block = (b, h, 64 q-rows). 4 waves split the k range in 4.
// Thread (lane) owns one q row entirely: Q row + O accumulator in registers,
// softmax state is two scalars (no online max: scores are bounded, m == 0).
// K/V rows are wave-uniform loads (coalesce to single line). Partials combine
// additively through LDS at the end.
// ============================================================================
#define KSPLIT 4
#define QT 64

__global__ __launch_bounds__(256, 2)
void attn_kernel(const float* __restrict__ ws,
                 const float* __restrict__ gate,
                 const int*   __restrict__ mask,
                 float* __restrict__ out)
{
    const float* Qws = ws;
    const float* Kws = ws + (size_t)(B_ * H_ * S_ * HD_);
    const float* Vws = ws + (size_t)2 * (B_ * H_ * S_ * HD_);

    // h = bid>>6 so the 8 sibling blocks (same b,qtile) are 64 apart -> same XCD
    const int bid = blockIdx.x;
    const int h   = bid >> 6;
    const int rem = bid & 63;
    const int b   = rem >> 5;
    const int qt  = rem & 31;
    const int q0  = qt * QT;

    const int t    = threadIdx.x;
    const int w    = t >> 6;
    const int lane = t & 63;
    const int q    = q0 + lane;

    // Q row -> registers
    const float4* Qr = reinterpret_cast<const float4*>(
        Qws + (((size_t)b * H_ + h) * S_ + q) * HD_);
    float4 qreg[16];
    #pragma unroll
    for (int i = 0; i < 16; ++i) qreg[i] = Qr[i];

    float4 o4[16];
    #pragma unroll
    for (int i = 0; i < 16; ++i) o4[i] = make_float4(0.f, 0.f, 0.f, 0.f);
    float l = 0.f;

    const float* Kbase = Kws + (((size_t)b * H_ + h) * S_) * HD_;
    const float* Vbase = Vws + (((size_t)b * H_ + h) * S_) * HD_;
    const float* gbase = gate + (((size_t)b * S_) * S_ + q) * H_ + h;   // + k*S_*H_
    const int4*  mrow  = reinterpret_cast<const int4*>(mask + ((size_t)b * S_ + q) * S_);

    const int kbeg = w * (S_ / KSPLIT);
    for (int k4 = 0; k4 < (S_ / KSPLIT) / 4; ++k4) {
        const int k = kbeg + k4 * 4;
        const int4 mv = mrow[k >> 2];
        const int mvals[4] = {mv.x, mv.y, mv.z, mv.w};
        #pragma unroll
        for (int j = 0; j < 4; ++j) {
            const int kk = k + j;
            const float4* Kr = reinterpret_cast<const float4*>(Kbase + (size_t)kk * HD_);
            float sx = 0.f, sy = 0.f, sz = 0.f, sw = 0.f;
            #pragma unroll
            for (int i = 0; i < 16; ++i) {
                float4 kv = Kr[i];
                sx = fmaf(qreg[i].x, kv.x, sx);
                sy = fmaf(qreg[i].y, kv.y, sy);
                sz = fmaf(qreg[i].z, kv.z, sz);
                sw = fmaf(qreg[i].w, kv.w, sw);
            }
            float s = (sx + sy) + (sz + sw);
            float g = gbase[(size_t)kk * (S_ * H_)];
            s = fmaf(s, 0.125f, g);                     // QK/sqrt(HD) + gate
            float p = mvals[j] ? __expf(s) : 0.f;       // mask==0 -> exactly 0 weight
            l += p;
            const float4* Vr = reinterpret_cast<const float4*>(Vbase + (size_t)kk * HD_);
            #pragma unroll
            for (int i = 0; i < 16; ++i) {
                float4 vv = Vr[i];
                o4[i].x = fmaf(p, vv.x, o4[i].x);
                o4[i].y = fmaf(p, vv.y, o4[i].y);
                o4[i].z = fmaf(p, vv.z, o4[i].z);
                o4[i].w = fmaf(p, vv.w, o4[i].w);
            }
        }
    }

    // ---- combine the 4 k-split partials (pure adds since max term is fixed) ----
    __shared__ float Olds[2 * HD_ * 65];   // [slot][hd][65]  (odd stride -> 2-way max)
    __shared__ float lred[2 * 64];

    if (w >= 2) {                          // waves 2,3 dump
        const int slot = w - 2;
        #pragma unroll
        for (int i = 0; i < 16; ++i) {
            Olds[(slot * 64 + i * 4 + 0) * 65 + lane] = o4[i].x;
            Olds[(slot * 64 + i * 4 + 1) * 65 + lane] = o4[i].y;
            Olds[(slot * 64 + i * 4 + 2) * 65 + lane] = o4[i].z;
            Olds[(slot * 64 + i * 4 + 3) * 65 + lane] = o4[i].w;
        }
        lred[slot * 64 + lane] = l;
    }
    __syncthreads();
    if (w < 2) {                           // waves 0,1 absorb partner (w+2)
        const int slot = w;
        #pragma unroll
        for (int i = 0; i < 16; ++i) {
            o4[i].x += Olds[(slot * 64 + i * 4 + 0) * 65 + lane];
            o4[i].y += Olds[(slot * 64 + i * 4 + 1) * 65 + lane];
            o4[i].z += Olds[(slot * 64 + i * 4 + 2) * 65 + lane];
            o4[i].w += Olds[(slot * 64 + i * 4 + 3) * 65 + lane];
        }
        l += lred[slot * 64 + lane];
    }
    __syncthreads();
    if (w < 2) {                           // waves 0,1 publish combined halves
        #pragma unroll
        for (int i = 0; i < 16; ++i) {
            Olds[(w * 64 + i * 4 + 0) * 65 + lane] = o4[i].x;
            Olds[(w * 64 + i * 4 + 1) * 65 + lane] = o4[i].y;
            Olds[(w * 64 + i * 4 + 2) * 65 + lane] = o4[i].z;
            Olds[(w * 64 + i * 4 + 3) * 65 + lane] = o4[i].w;
        }
        lred[w * 64 + lane] = l;
    }
    __syncthreads();

    // final: lane = hd (coalesced 256B stores), each thread covers 16 q rows
    const int hd = t & 63;
    #pragma unroll
    for (int r = 0; r < 16; ++r) {
        const int qq = (t >> 6) * 16 + r;
        float lsum = lred[qq] + lred[64 + qq];
        float v = Olds[hd * 65 + qq] + Olds[(64 + hd) * 65 + qq];
        out[((size_t)b * S_ + q0 + qq) * D_ + h * HD_ + hd] = v / lsum;
    }
}

// ============================================================================
extern "C" void kernel_launch(void* const* d_in, const int* in_sizes, int n_in,
                              void* d_out, int out_size, void* d_ws, size_t ws_size,
                              hipStream_t stream)
{
    const float* queries = (const float*)d_in[0];
    const float* keys    = (const float*)d_in[1];
    const float* values  = (const float*)d_in[2];
    const float* gate    = (const float*)d_in[3];
    const int*   mask    = (const int*)  d_in[4];
    const float* Wq      = (const float*)d_in[5];
    const float* bq      = (const float*)d_in[6];
    const float* Wk      = (const float*)d_in[7];
    const float* bk      = (const float*)d_in[8];
    const float* Wv      = (const float*)d_in[9];
    const float* bv      = (const float*)d_in[10];

    float* ws  = (float*)d_ws;   // Q | K | V each B*H*S*HD fp32 (8 MiB each)
    float* out = (float*)d_out;

    dim3 pgrid(4096 / PBM, D_ / PBN, 3);
    proj_kernel<<<pgrid, 256, 0, stream>>>(queries, keys, values,
                                           Wq, bq, Wk, bk, Wv, bv, ws);

    attn_kernel<<<B_ * H_ * (S_ / QT), 256, 0, stream>>>(ws, gate, mask, out);
}

// Round 2
// 659.263 us; speedup vs baseline: 2.9520x; 2.9520x over previous
//
#include <hip/hip_runtime.h>
#include <hip/hip_bf16.h>

#define B_  2
#define S_  2048
#define D_  512
#define H_  8
#define HD_ 64
#define WSN 2097152   // elements per bf16 plane (B*H*S*HD)

typedef __attribute__((ext_vector_type(8))) short short8v;
typedef __attribute__((ext_vector_type(4))) float f32x4;

union U8 { ushort s[8]; uint4 v; };

__device__ __forceinline__ ushort f2bf(float x) {          // RNE float->bf16 bits
    union { float f; unsigned u; } c; c.f = x;
    unsigned r = c.u + 0x7fffu + ((c.u >> 16) & 1u);
    return (ushort)(r >> 16);
}
__device__ __forceinline__ float bf2f(ushort b) {
    union { unsigned u; float f; } c; c.u = ((unsigned)b) << 16;
    return c.f;
}
__device__ __forceinline__ unsigned shflu(unsigned v, int src) {
    return (unsigned)__shfl((int)v, src, 64);
}

#define MFMA(a, b, c) __builtin_amdgcn_mfma_f32_16x16x32_bf16((a), (b), (c), 0, 0, 0)

// ============================================================================
// Projection via split-bf16 MFMA (3 passes: Ah*Bh + Al*Bh + Ah*Bl).
// which 0/1 (Q/K): write row-major [B,H,S,HD] hi/lo.  which 2 (V): write
// transposed [B,H,HD,S] hi/lo via LDS bounce.
// ============================================================================
#define PM 128
#define PN 64
#define PK 32

__global__ __launch_bounds__(256, 3)
void proj_kernel(const float* __restrict__ Xq, const float* __restrict__ Xk,
                 const float* __restrict__ Xv,
                 const float* __restrict__ Wq, const float* __restrict__ bq,
                 const float* __restrict__ Wk, const float* __restrict__ bk,
                 const float* __restrict__ Wv, const float* __restrict__ bv,
                 ushort* __restrict__ ws)
{
    const int which = blockIdx.z;
    const float* X    = which == 0 ? Xq : (which == 1 ? Xk : Xv);
    const float* W    = which == 0 ? Wq : (which == 1 ? Wk : Wv);
    const float* bias = which == 0 ? bq : (which == 1 ? bk : bv);
    ushort* outh = ws + (size_t)which * 2 * WSN;
    ushort* outl = outh + WSN;

    __shared__ __align__(16) char smem[33792];
    ushort (*Ah)[40]  = (ushort(*)[40])(smem);            // 128x40
    ushort (*Al)[40]  = (ushort(*)[40])(smem + 10240);
    ushort (*Bh)[40]  = (ushort(*)[40])(smem + 20480);    // 64x40
    ushort (*Bl)[40]  = (ushort(*)[40])(smem + 25600);
    float  (*VT)[132] = (float(*)[132])(smem);            // epilogue alias 64x132 f32

    const int t = threadIdx.x;
    const int lane = t & 63, wid = t >> 6;
    const int g = lane >> 4, ql = lane & 15;
    const int wm = wid >> 1, wn = wid & 1;
    const int m0 = blockIdx.x * PM, n0 = blockIdx.y * PN;

    const int arow = t >> 1, ahalf = (t & 1) * 16;   // A stage: 16 floats/thread
    const int brow = t >> 2, bcol = (t & 3) * 8;     // B stage: 8 floats/thread

    f32x4 acc[4][2];
    #pragma unroll
    for (int i = 0; i < 4; ++i)
        #pragma unroll
        for (int j = 0; j < 2; ++j) acc[i][j] = (f32x4)(0.0f);

    for (int k0 = 0; k0 < D_; k0 += PK) {
        // ---- stage fp32 -> bf16 hi/lo into LDS ----
        {
            const float* xp = &X[(size_t)(m0 + arow) * D_ + k0 + ahalf];
            float av[16];
            #pragma unroll
            for (int i = 0; i < 4; ++i) {
                float4 f = *(const float4*)&xp[i * 4];
                av[i*4+0] = f.x; av[i*4+1] = f.y; av[i*4+2] = f.z; av[i*4+3] = f.w;
            }
            #pragma unroll
            for (int hh = 0; hh < 2; ++hh) {
                U8 uh, ul;
                #pragma unroll
                for (int i = 0; i < 8; ++i) {
                    float v = av[hh*8 + i];
                    ushort hb = f2bf(v);
                    uh.s[i] = hb; ul.s[i] = f2bf(v - bf2f(hb));
                }
                *(uint4*)&Ah[arow][ahalf + hh*8] = uh.v;
                *(uint4*)&Al[arow][ahalf + hh*8] = ul.v;
            }
            const float* wp = &W[(size_t)(n0 + brow) * D_ + k0 + bcol];
            float4 f0 = *(const float4*)&wp[0], f1 = *(const float4*)&wp[4];
            float bw[8] = {f0.x, f0.y, f0.z, f0.w, f1.x, f1.y, f1.z, f1.w};
            U8 uh, ul;
            #pragma unroll
            for (int i = 0; i < 8; ++i) {
                ushort hb = f2bf(bw[i]);
                uh.s[i] = hb; ul.s[i] = f2bf(bw[i] - bf2f(hb));
            }
            *(uint4*)&Bh[brow][bcol] = uh.v;
            *(uint4*)&Bl[brow][bcol] = ul.v;
        }
        __syncthreads();
        // ---- MFMA: one K=32 step ----
        short8v afh[4], afl[4], bfh[2], bfl[2];
        #pragma unroll
        for (int mf = 0; mf < 4; ++mf) {
            afh[mf] = *(const short8v*)&Ah[wm*64 + mf*16 + ql][g*8];
            afl[mf] = *(const short8v*)&Al[wm*64 + mf*16 + ql][g*8];
        }
        #pragma unroll
        for (int nf = 0; nf < 2; ++nf) {
            bfh[nf] = *(const short8v*)&Bh[wn*32 + nf*16 + ql][g*8];
            bfl[nf] = *(const short8v*)&Bl[wn*32 + nf*16 + ql][g*8];
        }
        #pragma unroll
        for (int mf = 0; mf < 4; ++mf)
            #pragma unroll
            for (int nf = 0; nf < 2; ++nf) {
                acc[mf][nf] = MFMA(afh[mf], bfh[nf], acc[mf][nf]);
                acc[mf][nf] = MFMA(afl[mf], bfh[nf], acc[mf][nf]);
                acc[mf][nf] = MFMA(afh[mf], bfl[nf], acc[mf][nf]);
            }
        __syncthreads();
    }

    // ---- epilogue ----
    float bias2[2];
    #pragma unroll
    for (int nf = 0; nf < 2; ++nf) bias2[nf] = bias[n0 + wn*32 + nf*16 + ql];

    if (which < 2) {
        // D[m][n]: col n = lane&15, row m = g*4 + r   -> [B,H,S,HD]
        #pragma unroll
        for (int mf = 0; mf < 4; ++mf)
            #pragma unroll
            for (int nf = 0; nf < 2; ++nf)
                #pragma unroll
                for (int r = 0; r < 4; ++r) {
                    int m = m0 + wm*64 + mf*16 + g*4 + r;
                    int s = m & (S_ - 1), bb = m >> 11;
                    int n = n0 + wn*32 + nf*16 + ql;
                    float v = acc[mf][nf][r] + bias2[nf];
                    ushort hb = f2bf(v), lb = f2bf(v - bf2f(hb));
                    size_t idx = ((size_t)(bb * H_ + (n >> 6)) * S_ + s) * HD_ + (n & 63);
                    outh[idx] = hb; outl[idx] = lb;
                }
    } else {
        // V: bounce through LDS, store transposed [B,H,HD,S]
        #pragma unroll
        for (int mf = 0; mf < 4; ++mf)
            #pragma unroll
            for (int nf = 0; nf < 2; ++nf)
                #pragma unroll
                for (int r = 0; r < 4; ++r)
                    VT[wn*32 + nf*16 + ql][wm*64 + mf*16 + g*4 + r] =
                        acc[mf][nf][r] + bias2[nf];
        __syncthreads();
        const int row = t >> 2, seg = (t & 3) * 32;
        const int h = n0 >> 6, bb = m0 >> 11, s0 = m0 & (S_ - 1);
        ushort* oh = outh + ((size_t)(bb * H_ + h) * HD_ + row) * S_ + s0 + seg;
        ushort* ol = outl + ((size_t)(bb * H_ + h) * HD_ + row) * S_ + s0 + seg;
        #pragma unroll
        for (int c0 = 0; c0 < 32; c0 += 8) {
            U8 uh, ul;
            #pragma unroll
            for (int i = 0; i < 8; ++i) {
                float v = VT[row][seg + c0 + i];
                ushort hb = f2bf(v);
                uh.s[i] = hb; ul.s[i] = f2bf(v - bf2f(hb));
            }
            *(uint4*)&oh[c0] = uh.v;
            *(uint4*)&ol[c0] = ul.v;
        }
    }
}

// ============================================================================
// Attention: block = (b, h, 64 q), 4 waves x 16 q each. Swapped QK^T:
// D_S[k][q] (col=q=lane&15, row=k=g*4+reg) -> softmax fully lane-local.
// K frags read from global (L2-shared across all q-blocks of (b,h)).
// V^T staged in LDS. P redistributed to A-frag layout via shuffles.
// ============================================================================
__global__ __launch_bounds__(256, 2)
void attn_kernel(const ushort* __restrict__ ws,
                 const float* __restrict__ gate,
                 const int*   __restrict__ mask,
                 float* __restrict__ out)
{
    const ushort* Qh  = ws;
    const ushort* Qlo = ws + (size_t)WSN;
    const ushort* Kh  = ws + (size_t)2 * WSN;
    const ushort* Klo = ws + (size_t)3 * WSN;
    const ushort* Vth = ws + (size_t)4 * WSN;
    const ushort* Vtl = ws + (size_t)5 * WSN;

    __shared__ ushort VhL[64][72], VlL[64][72];   // [hd][k] padded (2-way max)

    // h in high bits: 8 sibling blocks (same b,qt) are 64 apart -> same XCD
    const int bid = blockIdx.x;
    const int h = bid >> 6, b = (bid >> 5) & 1, qt = bid & 31;
    const int q0 = qt * 64;

    const int t = threadIdx.x, lane = t & 63, wid = t >> 6;
    const int g = lane >> 4, ql = lane & 15;
    const int qg = q0 + wid * 16 + ql;            // this lane's q column

    const size_t bh = (size_t)(b * H_ + h);
    const ushort* Kbh = Kh  + bh * S_ * HD_;
    const ushort* Kbl = Klo + bh * S_ * HD_;
    const ushort* Vbh = Vth + bh * HD_ * S_;
    const ushort* Vbl = Vtl + bh * HD_ * S_;
    const float*  gb  = gate + (size_t)b * S_ * S_ * H_ + (size_t)qg * H_ + h;
    const int*    mb  = mask + ((size_t)b * S_ + qg) * S_;

    // Q fragments (hoisted): B-operand, col=q=lane&15, c=hd=g*8+j
    short8v qfh[2], qfl[2];
    {
        const ushort* qr = Qh  + (bh * S_ + qg) * HD_;
        const ushort* qrl = Qlo + (bh * S_ + qg) * HD_;
        #pragma unroll
        for (int c2 = 0; c2 < 2; ++c2) {
            qfh[c2] = *(const short8v*)&qr[c2*32 + g*8];
            qfl[c2] = *(const short8v*)&qrl[c2*32 + g*8];
        }
    }

    f32x4 accO[4];
    #pragma unroll
    for (int i = 0; i < 4; ++i) accO[i] = (f32x4)(0.0f);
    float lpart = 0.0f;

    const int srcA = ql + ((g & 1) << 5);   // P-shuffle source lanes
    const int srcB = srcA + 16;

    for (int kt = 0; kt < S_ / 64; ++kt) {
        const int k00 = kt * 64;
        __syncthreads();                    // protect LDS from prev readers
        // ---- gate + mask (issue early) ----
        int4 mv[4]; float gv[4][4];
        #pragma unroll
        for (int kf = 0; kf < 4; ++kf)
            mv[kf] = *(const int4*)&mb[k00 + kf*16 + g*4];
        #pragma unroll
        for (int kf = 0; kf < 4; ++kf)
            #pragma unroll
            for (int r = 0; r < 4; ++r)
                gv[kf][r] = gb[(size_t)(k00 + kf*16 + g*4 + r) * (S_ * H_)];
        // ---- stage V^T tile into LDS ----
        #pragma unroll
        for (int i = 0; i < 2; ++i) {
            int ch = t + i * 256;
            int r = ch >> 3, c = (ch & 7) * 8;
            *(uint4*)&VhL[r][c] = *(const uint4*)&Vbh[(size_t)r * S_ + k00 + c];
            *(uint4*)&VlL[r][c] = *(const uint4*)&Vbl[(size_t)r * S_ + k00 + c];
        }
        __syncthreads();

        // ---- S^T = K·Q (A=K rows k from global, B=Q cols q) ----
        f32x4 accS[4];
        #pragma unroll
        for (int kf = 0; kf < 4; ++kf) accS[kf] = (f32x4)(0.0f);
        #pragma unroll
        for (int kf = 0; kf < 4; ++kf) {
            const ushort* krh = Kbh + (size_t)(k00 + kf*16 + ql) * HD_;
            const ushort* krl = Kbl + (size_t)(k00 + kf*16 + ql) * HD_;
            short8v kh0 = *(const short8v*)&krh[g*8];
            short8v kh1 = *(const short8v*)&krh[32 + g*8];
            short8v kl0 = *(const short8v*)&krl[g*8];
            short8v kl1 = *(const short8v*)&krl[32 + g*8];
            f32x4 a = accS[kf];
            a = MFMA(kh0, qfh[0], a); a = MFMA(kh1, qfh[1], a);
            a = MFMA(kl0, qfh[0], a); a = MFMA(kl1, qfh[1], a);
            a = MFMA(kh0, qfl[0], a); a = MFMA(kh1, qfl[1], a);
            accS[kf] = a;
        }

        // ---- softmax numerators (lane-local), pack bf16 hi/lo ----
        unsigned phw[4][2], plw[4][2];
        #pragma unroll
        for (int kf = 0; kf < 4; ++kf) {
            float p[4];
            #pragma unroll
            for (int r = 0; r < 4; ++r) {
                float s = fmaf(accS[kf][r], 0.125f, gv[kf][r]);
                const int mm = (r == 0) ? mv[kf].x : (r == 1) ? mv[kf].y
                             : (r == 2) ? mv[kf].z : mv[kf].w;
                p[r] = mm ? __expf(s) : 0.0f;
                lpart += p[r];
            }
            ushort h0 = f2bf(p[0]), h1 = f2bf(p[1]), h2 = f2bf(p[2]), h3 = f2bf(p[3]);
            phw[kf][0] = ((unsigned)h1 << 16) | h0;
            phw[kf][1] = ((unsigned)h3 << 16) | h2;
            ushort l0 = f2bf(p[0] - bf2f(h0)), l1 = f2bf(p[1] - bf2f(h1));
            ushort l2 = f2bf(p[2] - bf2f(h2)), l3 = f2bf(p[3] - bf2f(h3));
            plw[kf][0] = ((unsigned)l1 << 16) | l0;
            plw[kf][1] = ((unsigned)l3 << 16) | l2;
        }

        // ---- redistribute P to PV A-frag layout (row q=lane&15, c k=g*8+j) ----
        short8v pah[2], pal[2];
        #pragma unroll
        for (int cc = 0; cc < 2; ++cc) {
            union { unsigned u[4]; short8v v; } Uh, Ul;
            #pragma unroll
            for (int w = 0; w < 2; ++w) {
                unsigned a0 = shflu(phw[2*cc][w], srcA);
                unsigned a1 = shflu(phw[2*cc + 1][w], srcA);
                Uh.u[w] = (g >= 2) ? a1 : a0;
                unsigned b0 = shflu(phw[2*cc][w], srcB);
                unsigned b1 = shflu(phw[2*cc + 1][w], srcB);
                Uh.u[2 + w] = (g >= 2) ? b1 : b0;
                unsigned c0 = shflu(plw[2*cc][w], srcA);
                unsigned c1 = shflu(plw[2*cc + 1][w], srcA);
                Ul.u[w] = (g >= 2) ? c1 : c0;
                unsigned d0 = shflu(plw[2*cc][w], srcB);
                unsigned d1 = shflu(plw[2*cc + 1][w], srcB);
                Ul.u[2 + w] = (g >= 2) ? d1 : d0;
            }
            pah[cc] = Uh.v; pal[cc] = Ul.v;
        }

        // ---- O += P·V  (B=V^T from LDS: col hd=lane&15, c k=g*8+j) ----
        #pragma unroll
        for (int nf = 0; nf < 4; ++nf) {
            f32x4 a = accO[nf];
            #pragma unroll
            for (int cc = 0; cc < 2; ++cc) {
                short8v vh = *(const short8v*)&VhL[nf*16 + ql][cc*32 + g*8];
                short8v vl = *(const short8v*)&VlL[nf*16 + ql][cc*32 + g*8];
                a = MFMA(pah[cc], vh, a);
                a = MFMA(pal[cc], vh, a);
                a = MFMA(pah[cc], vl, a);
            }
            accO[nf] = a;
        }
    }

    // ---- denominator: reduce across the 4 lane-groups, fetch per-row ----
    lpart += __shfl_xor(lpart, 16, 64);
    lpart += __shfl_xor(lpart, 32, 64);
    float lrow[4];
    #pragma unroll
    for (int r = 0; r < 4; ++r) lrow[r] = __shfl(lpart, g*4 + r, 64);

    // ---- store: O[q][hd], col hd = lane&15, row q = g*4 + r ----
    #pragma unroll
    for (int nf = 0; nf < 4; ++nf)
        #pragma unroll
        for (int r = 0; r < 4; ++r) {
            int qq = q0 + wid*16 + g*4 + r;
            out[((size_t)b * S_ + qq) * D_ + h * HD_ + nf*16 + ql] =
                accO[nf][r] / lrow[r];
        }
}

// ============================================================================
extern "C" void kernel_launch(void* const* d_in, const int* in_sizes, int n_in,
                              void* d_out, int out_size, void* d_ws, size_t ws_size,
                              hipStream_t stream)
{
    const float* queries = (const float*)d_in[0];
    const float* keys    = (const float*)d_in[1];
    const float* values  = (const float*)d_in[2];
    const float* gate    = (const float*)d_in[3];
    const int*   mask    = (const int*)  d_in[4];
    const float* Wq      = (const float*)d_in[5];
    const float* bq      = (const float*)d_in[6];
    const float* Wk      = (const float*)d_in[7];
    const float* bk      = (const float*)d_in[8];
    const float* Wv      = (const float*)d_in[9];
    const float* bv      = (const float*)d_in[10];

    ushort* ws = (ushort*)d_ws;   // Qh|Ql|Kh|Kl|Vth|Vtl, 6 x 4 MB = 24 MB
    float* outp = (float*)d_out;

    proj_kernel<<<dim3(4096 / PM, D_ / PN, 3), 256, 0, stream>>>(
        queries, keys, values, Wq, bq, Wk, bk, Wv, bv, ws);

    attn_kernel<<<dim3(B_ * H_ * (S_ / 64)), 256, 0, stream>>>(
        ws, gate, mask, outp);
}

// Round 5
// 651.229 us; speedup vs baseline: 2.9884x; 1.0123x over previous
//
#include <hip/hip_runtime.h>

#define B_  2
#define S_  2048
#define D_  512
#define H_  8
#define HD_ 64

typedef __attribute__((ext_vector_type(8))) short short8v;
typedef __attribute__((ext_vector_type(4))) float f32x4;

union U8 { ushort s[8]; uint4 v; };
union Hu { ushort u; _Float16 h; };

__device__ __forceinline__ ushort f2bf(float x) {          // RNE float->bf16 bits
    union { float f; unsigned u; } c; c.f = x;
    unsigned r = c.u + 0x7fffu + ((c.u >> 16) & 1u);
    return (ushort)(r >> 16);
}
__device__ __forceinline__ float bf2f(ushort b) {
    union { unsigned u; float f; } c; c.u = ((unsigned)b) << 16;
    return c.f;
}
__device__ __forceinline__ unsigned shflu(unsigned v, int src) {
    return (unsigned)__shfl((int)v, src, 64);
}
__device__ __forceinline__ void gl2lds(const void* g, void* l) {
    auto g1 = (const __attribute__((address_space(1))) char*)(uintptr_t)g;
    auto l3 = (__attribute__((address_space(3))) char*)(uint32_t)(uintptr_t)l;
    __builtin_amdgcn_global_load_lds(g1, l3, 16, 0, 0);
}

#define MFMA(a, b, c) __builtin_amdgcn_mfma_f32_16x16x32_bf16((a), (b), (c), 0, 0, 0)

// ---- ws layout (ushort element offsets unless noted) ----
#define OFF_QH  67108864ull
#define OFF_QL  69206016ull
#define OFF_KH  71303168ull
#define OFF_KL  73400320ull
#define OFF_VTH 75497472ull
#define OFF_VTL 77594624ull
#define OFF_XH  79691776ull
#define OFF_XL  85983232ull
#define OFF_WH  92274688ull
#define OFF_WL  93061120ull
#define PARTO_BYTE 159383552ull    // aliases X/W region (dead by attn time)

// ============================================================================
// Prepass A: gate [b,k,q,h] fp32 + mask [b,1,q,k] -> gT[b,h,k,q] fp16,
// masked entries = -60000 (fp16 0xFB53) so exp() underflows to exact 0.
// ============================================================================
__global__ __launch_bounds__(256)
void gate_prep(const float* __restrict__ gate, const int* __restrict__ mask,
               ushort* __restrict__ gT)
{
    const int b = blockIdx.z, k0 = blockIdx.x * 64, q0 = blockIdx.y * 64;
    const int t = threadIdx.x;
    const int qb = (t & 7) * 8;
    #pragma unroll
    for (int p = 0; p < 2; ++p) {
        const int k = p * 32 + (t >> 3);
        const float* gp = gate + (((size_t)b * S_ + k0 + k) * S_ + q0 + qb) * H_;
        const int*   mp = mask + ((size_t)b * S_ + q0 + qb) * S_ + k0 + k;
        ushort oh[8][8];
        #pragma unroll
        for (int j = 0; j < 8; ++j) {
            float4 f0 = *(const float4*)(gp + (size_t)j * 8);
            float4 f1 = *(const float4*)(gp + (size_t)j * 8 + 4);
            int m = mp[(size_t)j * S_];
            float vals[8] = {f0.x, f0.y, f0.z, f0.w, f1.x, f1.y, f1.z, f1.w};
            #pragma unroll
            for (int hh = 0; hh < 8; ++hh) {
                Hu c; c.h = (_Float16)vals[hh];
                oh[hh][j] = m ? c.u : (ushort)0xFB53;
            }
        }
        #pragma unroll
        for (int hh = 0; hh < 8; ++hh) {
            U8 u;
            #pragma unroll
            for (int j = 0; j < 8; ++j) u.s[j] = oh[hh][j];
            *(uint4*)&gT[((size_t)(b * 8 + hh) * S_ + k0 + k) * S_ + q0 + qb] = u.v;
        }
    }
}

// ============================================================================
// Prepass B: fp32 -> bf16 hi/lo split (elementwise). 3 sources via blockIdx.y.
// ============================================================================
__global__ __launch_bounds__(256)
void cvt_kernel(const float* __restrict__ s0, const float* __restrict__ s1,
                const float* __restrict__ s2, ushort* __restrict__ dh,
                ushort* __restrict__ dl, int per8)
{
    const int which = blockIdx.y;
    const float* s = which == 0 ? s0 : (which == 1 ? s1 : s2);
    const size_t base = (size_t)which * per8 * 8;
    const size_t idx = (size_t)blockIdx.x * 256 + threadIdx.x;
    float4 f0 = *((const float4*)s + idx * 2);
    float4 f1 = *((const float4*)s + idx * 2 + 1);
    float v[8] = {f0.x, f0.y, f0.z, f0.w, f1.x, f1.y, f1.z, f1.w};
    U8 uh, ul;
    #pragma unroll
    for (int i = 0; i < 8; ++i) {
        ushort hb = f2bf(v[i]);
        uh.s[i] = hb; ul.s[i] = f2bf(v[i] - bf2f(hb));
    }
    *(uint4*)&dh[base + idx * 8] = uh.v;
    *(uint4*)&dl[base + idx * 8] = ul.v;
}

// ============================================================================
// Projection: bf16 split GEMM, m97 recipe. Tile 128Mx64N, BK=64, 4 waves 2x2.
// XOR-swizzled LDS via pre-swizzled global_load_lds source. Q scaled by 1/8.
// ============================================================================
__global__ __launch_bounds__(256, 3)
void proj_kernel(const float* __restrict__ bq, const float* __restrict__ bk,
                 const float* __restrict__ bv, ushort* __restrict__ ws16)
{
    const int which = blockIdx.z;
    const int h = blockIdx.y;
    const int m0 = blockIdx.x * 128;
    const float* bias = which == 0 ? bq : (which == 1 ? bk : bv);

    const ushort* xh = ws16 + OFF_XH + (size_t)which * 2097152;
    const ushort* xl = ws16 + OFF_XL + (size_t)which * 2097152;
    const ushort* wh = ws16 + OFF_WH + (size_t)which * 262144;
    const ushort* wl = ws16 + OFF_WL + (size_t)which * 262144;

    __shared__ __align__(16) ushort plds[24576];  // Ah|Al|Bh|Bl = 16K|16K|8K|8K bytes

    const int t = threadIdx.x, lane = t & 63, wid = t >> 6;
    const int g = lane >> 4, ql = lane & 15;
    const int wm = wid >> 1, wn = wid & 1;
    const int n0 = h * 64;

    f32x4 acc[4][2];
    #pragma unroll
    for (int i = 0; i < 4; ++i)
        #pragma unroll
        for (int j = 0; j < 2; ++j) acc[i][j] = (f32x4)(0.0f);

    for (int k0 = 0; k0 < D_; k0 += 64) {
        // ---- stage (linear LDS dest, pre-swizzled global source) ----
        #pragma unroll
        for (int c = 0; c < 4; ++c) {
            int ch = c * 256 + t;
            int row = ch >> 3, cb = ch & 7;
            size_t so = (size_t)(m0 + row) * 512 + k0 + ((cb ^ (row & 7)) * 8);
            gl2lds(xh + so, (char*)plds + c * 4096 + wid * 1024);
            gl2lds(xl + so, (char*)plds + 16384 + c * 4096 + wid * 1024);
        }
        #pragma unroll
        for (int c = 0; c < 2; ++c) {
            int ch = c * 256 + t;
            int row = ch >> 3, cb = ch & 7;
            size_t so = (size_t)(n0 + row) * 512 + k0 + ((cb ^ (row & 7)) * 8);
            gl2lds(wh + so, (char*)plds + 32768 + c * 4096 + wid * 1024);
            gl2lds(wl + so, (char*)plds + 40960 + c * 4096 + wid * 1024);
        }
        __syncthreads();
        // ---- compute ----
        #pragma unroll
        for (int ks = 0; ks < 2; ++ks) {
            short8v ah[4], al[4], bh2[2], bl2[2];
            #pragma unroll
            for (int mf = 0; mf < 4; ++mf) {
                int r = wm * 64 + mf * 16 + ql;
                int cb = ((ks * 4 + g) ^ (r & 7)) * 8;
                ah[mf] = *(const short8v*)&plds[r * 64 + cb];
                al[mf] = *(const short8v*)&plds[8192 + r * 64 + cb];
            }
            #pragma unroll
            for (int nf = 0; nf < 2; ++nf) {
                int n = wn * 32 + nf * 16 + ql;
                int cb = ((ks * 4 + g) ^ (n & 7)) * 8;
                bh2[nf] = *(const short8v*)&plds[16384 + n * 64 + cb];
                bl2[nf] = *(const short8v*)&plds[20480 + n * 64 + cb];
            }
            #pragma unroll
            for (int mf = 0; mf < 4; ++mf)
                #pragma unroll
                for (int nf = 0; nf < 2; ++nf) {
                    acc[mf][nf] = MFMA(ah[mf], bh2[nf], acc[mf][nf]);
                    acc[mf][nf] = MFMA(al[mf], bh2[nf], acc[mf][nf]);
                    acc[mf][nf] = MFMA(ah[mf], bl2[nf], acc[mf][nf]);
                }
        }
        __syncthreads();
    }

    const int bb = m0 >> 11, s0 = m0 & 2047;
    float b0 = bias[n0 + wn * 32 + ql];
    float b1 = bias[n0 + wn * 32 + 16 + ql];

    if (which < 2) {
        const float scale = (which == 0) ? 0.125f : 1.0f;
        ushort* oh = ws16 + (which == 0 ? OFF_QH : OFF_KH);
        ushort* ol = ws16 + (which == 0 ? OFF_QL : OFF_KL);
        #pragma unroll
        for (int mf = 0; mf < 4; ++mf)
            #pragma unroll
            for (int nf = 0; nf < 2; ++nf)
                #pragma unroll
                for (int r = 0; r < 4; ++r) {
                    int s = s0 + wm * 64 + mf * 16 + g * 4 + r;
                    int n = wn * 32 + nf * 16 + ql;
                    float v = (acc[mf][nf][r] + (nf ? b1 : b0)) * scale;
                    ushort hb = f2bf(v), lb = f2bf(v - bf2f(hb));
                    size_t idx = ((size_t)(bb * 8 + h) * S_ + s) * 64 + n;
                    oh[idx] = hb; ol[idx] = lb;
                }
    } else {
        float (*VT)[132] = (float(*)[132])plds;   // 64 x 132 f32 (33.8 KB)
        #pragma unroll
        for (int mf = 0; mf < 4; ++mf)
            #pragma unroll
            for (int nf = 0; nf < 2; ++nf)
                #pragma unroll
                for (int r = 0; r < 4; ++r)
                    VT[wn * 32 + nf * 16 + ql][wm * 64 + mf * 16 + g * 4 + r] =
                        acc[mf][nf][r] + (nf ? b1 : b0);
        __syncthreads();
        const int row = t >> 2, seg = (t & 3) * 32;
        ushort* oh = ws16 + OFF_VTH;
        ushort* ol = ws16 + OFF_VTL;
        size_t ob = ((size_t)(bb * 8 + h) * 64 + row) * S_ + s0 + seg;
        #pragma unroll
        for (int c0 = 0; c0 < 32; c0 += 8) {
            U8 uh, ul;
            #pragma unroll
            for (int i = 0; i < 8; ++i) {
                float v = VT[row][seg + c0 + i];
                ushort hb = f2bf(v);
                uh.s[i] = hb; ul.s[i] = f2bf(v - bf2f(hb));
            }
            *(uint4*)&oh[ob + c0] = uh.v;
            *(uint4*)&ol[ob + c0] = ul.v;
        }
    }
}

// ============================================================================
// Attention: block = (b,h, 64q, k-quarter). Swapped QK^T, lane-local softmax,
// gate fp16 [b,h,k,q] reads, V^T in XOR-swizzled LDS via global_load_lds.
// Writes partial O / l; combine kernel reduces 4 k-splits.
// ============================================================================
__global__ __launch_bounds__(256, 4)
void attn_kernel(const ushort* __restrict__ ws16,
                 float* __restrict__ partO, float* __restrict__ partl)
{
    __shared__ __align__(16) ushort vlds[8192];   // Vh [0,4096) | Vl [4096,8192) ushorts

    // XCD chunking: blocks with same (b,h,ks) land on one XCD (K/V L2 reuse)
    const int orig = (blockIdx.x & 7) * 256 + (blockIdx.x >> 3);
    const int qt = orig & 31, ks = (orig >> 5) & 3, bh = orig >> 7;  // bh = b*8+h
    const int q0 = qt * 64, kbase = ks * 512;

    const int t = threadIdx.x, lane = t & 63, wid = t >> 6;
    const int g = lane >> 4, ql = lane & 15;
    const int qg = q0 + wid * 16 + ql;

    const ushort* Qhp = ws16 + OFF_QH + (size_t)bh * 131072;
    const ushort* Qlp = ws16 + OFF_QL + (size_t)bh * 131072;
    const ushort* Khp = ws16 + OFF_KH + (size_t)bh * 131072;
    const ushort* Klp = ws16 + OFF_KL + (size_t)bh * 131072;
    const ushort* Vhp = ws16 + OFF_VTH + (size_t)bh * 131072;
    const ushort* Vlp = ws16 + OFF_VTL + (size_t)bh * 131072;
    const ushort* gb  = ws16 + (size_t)bh * S_ * S_ + qg;

    short8v qfh[2], qfl[2];
    #pragma unroll
    for (int c2 = 0; c2 < 2; ++c2) {
        qfh[c2] = *(const short8v*)&Qhp[(size_t)qg * 64 + c2 * 32 + g * 8];
        qfl[c2] = *(const short8v*)&Qlp[(size_t)qg * 64 + c2 * 32 + g * 8];
    }

    f32x4 accO[4];
    #pragma unroll
    for (int i = 0; i < 4; ++i) accO[i] = (f32x4)(0.0f);
    float lpart = 0.0f;

    const int srcA = ql + ((g & 1) << 5);
    const int srcB = srcA + 16;

    for (int kt = 0; kt < 8; ++kt) {
        const int k00 = kbase + kt * 64;
        __syncthreads();                    // LDS safe to overwrite
        // ---- stage V^T tile (linear LDS dest, pre-swizzled source) ----
        #pragma unroll
        for (int c = 0; c < 2; ++c) {
            int ch = c * 256 + t;
            int r = ch >> 3, cb = ch & 7;
            size_t so = (size_t)r * S_ + k00 + ((cb ^ (r & 7)) * 8);
            gl2lds(Vhp + so, (char*)vlds + c * 4096 + wid * 1024);
            gl2lds(Vlp + so, (char*)vlds + 8192 + c * 4096 + wid * 1024);
        }
        __syncthreads();                    // drains stage

        // ---- gate loads (consumed after QK; overlap with MFMAs) ----
        float gv[4][4];
        #pragma unroll
        for (int kf = 0; kf < 4; ++kf)
            #pragma unroll
            for (int r = 0; r < 4; ++r) {
                Hu c; c.u = gb[(size_t)(k00 + kf * 16 + g * 4 + r) * S_];
                gv[kf][r] = (float)c.h;
            }

        // ---- S^T = K·Q(scaled) ----
        f32x4 accS[4];
        #pragma unroll
        for (int kf = 0; kf < 4; ++kf) accS[kf] = (f32x4)(0.0f);
        #pragma unroll
        for (int kf = 0; kf < 4; ++kf) {
            const ushort* krh = Khp + (size_t)(k00 + kf * 16 + ql) * 64;
            const ushort* krl = Klp + (size_t)(k00 + kf * 16 + ql) * 64;
            short8v kh0 = *(const short8v*)&krh[g * 8];
            short8v kh1 = *(const short8v*)&krh[32 + g * 8];
            short8v kl0 = *(const short8v*)&krl[g * 8];
            short8v kl1 = *(const short8v*)&krl[32 + g * 8];
            f32x4 a = accS[kf];
            a = MFMA(kh0, qfh[0], a); a = MFMA(kh1, qfh[1], a);
            a = MFMA(kl0, qfh[0], a); a = MFMA(kl1, qfh[1], a);
            a = MFMA(kh0, qfl[0], a); a = MFMA(kh1, qfl[1], a);
            accS[kf] = a;
        }

        // ---- softmax numerators (masked gate = -60000 -> exp == 0) ----
        unsigned phw[4][2], plw[4][2];
        #pragma unroll
        for (int kf = 0; kf < 4; ++kf) {
            float p[4];
            #pragma unroll
            for (int r = 0; r < 4; ++r) {
                p[r] = __expf(accS[kf][r] + gv[kf][r]);
                lpart += p[r];
            }
            ushort h0 = f2bf(p[0]), h1 = f2bf(p[1]), h2 = f2bf(p[2]), h3 = f2bf(p[3]);
            phw[kf][0] = ((unsigned)h1 << 16) | h0;
            phw[kf][1] = ((unsigned)h3 << 16) | h2;
            ushort l0 = f2bf(p[0] - bf2f(h0)), l1 = f2bf(p[1] - bf2f(h1));
            ushort l2 = f2bf(p[2] - bf2f(h2)), l3 = f2bf(p[3] - bf2f(h3));
            plw[kf][0] = ((unsigned)l1 << 16) | l0;
            plw[kf][1] = ((unsigned)l3 << 16) | l2;
        }

        // ---- redistribute P to A-frag layout ----
        short8v pah[2], pal[2];
        #pragma unroll
        for (int cc = 0; cc < 2; ++cc) {
            union { unsigned u[4]; short8v v; } Uh, Ul;
            #pragma unroll
            for (int w = 0; w < 2; ++w) {
                unsigned a0 = shflu(phw[2*cc][w], srcA);
                unsigned a1 = shflu(phw[2*cc + 1][w], srcA);
                Uh.u[w] = (g >= 2) ? a1 : a0;
                unsigned b0 = shflu(phw[2*cc][w], srcB);
                unsigned b1 = shflu(phw[2*cc + 1][w], srcB);
                Uh.u[2 + w] = (g >= 2) ? b1 : b0;
                unsigned c0 = shflu(plw[2*cc][w], srcA);
                unsigned c1 = shflu(plw[2*cc + 1][w], srcA);
                Ul.u[w] = (g >= 2) ? c1 : c0;
                unsigned d0 = shflu(plw[2*cc][w], srcB);
                unsigned d1 = shflu(plw[2*cc + 1][w], srcB);
                Ul.u[2 + w] = (g >= 2) ? d1 : d0;
            }
            pah[cc] = Uh.v; pal[cc] = Ul.v;
        }

        // ---- O += P·V (swizzled LDS reads, conflict-free) ----
        #pragma unroll
        for (int nf = 0; nf < 4; ++nf) {
            f32x4 a = accO[nf];
            #pragma unroll
            for (int cc = 0; cc < 2; ++cc) {
                int cb = ((cc * 4 + g) ^ (ql & 7)) * 8;
                short8v vh = *(const short8v*)&vlds[(nf * 16 + ql) * 64 + cb];
                short8v vl = *(const short8v*)&vlds[4096 + (nf * 16 + ql) * 64 + cb];
                a = MFMA(pah[cc], vh, a);
                a = MFMA(pal[cc], vh, a);
                a = MFMA(pah[cc], vl, a);
            }
            accO[nf] = a;
        }
    }

    // ---- write partials ----
    float* po = partO + (size_t)orig * 4096;
    #pragma unroll
    for (int nf = 0; nf < 4; ++nf)
        #pragma unroll
        for (int r = 0; r < 4; ++r)
            po[(wid * 16 + g * 4 + r) * 64 + nf * 16 + ql] = accO[nf][r];

    lpart += __shfl_xor(lpart, 16, 64);
    lpart += __shfl_xor(lpart, 32, 64);
    if (lane < 16) partl[(size_t)orig * 64 + wid * 16 + lane] = lpart;
}

// ============================================================================
// Combine: sum 4 k-split partials, divide, write [B,S,D] fp32.
// ============================================================================
__global__ __launch_bounds__(256)
void combine_kernel(const float* __restrict__ partO, const float* __restrict__ partl,
                    float* __restrict__ out)
{
    const int cid = blockIdx.x;
    const int bh = cid >> 5, qt = cid & 31;
    const int t = threadIdx.x;
    const int q = t >> 2, c4 = (t & 3) * 16;

    float4 sum[4];
    #pragma unroll
    for (int i = 0; i < 4; ++i) sum[i] = make_float4(0.f, 0.f, 0.f, 0.f);
    float l = 0.0f;

    #pragma unroll
    for (int ks = 0; ks < 4; ++ks) {
        int p = (bh * 4 + ks) * 32 + qt;
        const float* base = partO + (size_t)p * 4096 + q * 64 + c4;
        #pragma unroll
        for (int i = 0; i < 4; ++i) {
            float4 v = *(const float4*)(base + i * 4);
            sum[i].x += v.x; sum[i].y += v.y; sum[i].z += v.z; sum[i].w += v.w;
        }
        l += partl[(size_t)p * 64 + q];
    }
    float inv = 1.0f / l;
    const int b = bh >> 3, h = bh & 7;
    float* ob = out + ((size_t)b * S_ + qt * 64 + q) * D_ + h * 64 + c4;
    #pragma unroll
    for (int i = 0; i < 4; ++i) {
        float4 w = make_float4(sum[i].x * inv, sum[i].y * inv, sum[i].z * inv, sum[i].w * inv);
        *(float4*)(ob + i * 4) = w;
    }
}

// ============================================================================
extern "C" void kernel_launch(void* const* d_in, const int* in_sizes, int n_in,
                              void* d_out, int out_size, void* d_ws, size_t ws_size,
                              hipStream_t stream)
{
    const float* queries = (const float*)d_in[0];
    const float* keys    = (const float*)d_in[1];
    const float* values  = (const float*)d_in[2];
    const float* gate    = (const float*)d_in[3];
    const int*   mask    = (const int*)  d_in[4];
    const float* Wq      = (const float*)d_in[5];
    const float* bq      = (const float*)d_in[6];
    const float* Wk      = (const float*)d_in[7];
    const float* bk      = (const float*)d_in[8];
    const float* Wv      = (const float*)d_in[9];
    const float* bv      = (const float*)d_in[10];

    ushort* ws16 = (ushort*)d_ws;
    float* partO = (float*)((char*)d_ws + PARTO_BYTE);
    float* partl = partO + 8388608;
    float* outp  = (float*)d_out;

    // gate+mask -> fp16 transposed planes
    gate_prep<<<dim3(32, 32, 2), 256, 0, stream>>>(gate, mask, ws16);
    // X -> bf16 hi/lo (per8 = 4096*512/8)
    cvt_kernel<<<dim3(1024, 3), 256, 0, stream>>>(
        queries, keys, values, ws16 + OFF_XH, ws16 + OFF_XL, 262144);
    // W -> bf16 hi/lo (per8 = 512*512/8)
    cvt_kernel<<<dim3(128, 3), 256, 0, stream>>>(
        Wq, Wk, Wv, ws16 + OFF_WH, ws16 + OFF_WL, 32768);
    // projections (Q scaled by 1/8, V transposed)
    proj_kernel<<<dim3(32, 8, 3), 256, 0, stream>>>(bq, bk, bv, ws16);
    // attention with 4-way k-split
    attn_kernel<<<dim3(2048), 256, 0, stream>>>(ws16, partO, partl);
    // reduce partials
    combine_kernel<<<dim3(512), 256, 0, stream>>>(partO, partl, outp);
}